// Round 12
// baseline (1098.347 us; speedup 1.0000x reference)
//
#include <hip/hip_runtime.h>

// VQ: N=262144 rows, DIM=64, K=1024 codes.
// Single compute kernel: 16x16x32 bf16 MFMA, TWO-product split:
//   score = (xh + xl).eh = x.eh (exact to 2^-16), A = -2x as bf16 hi+lo,
//   B = bf16(e) ONLY (no e-lo array: halves B traffic and MFMA count).
//   Residual error = -2 sum x_i*el_i, sigma ~ 3.2e-2, worst ~0.2; expected
//   top-2 margin ~ 8.0 => eps 0.5 flags ~6% of rows for exact re-solve.
//   acc init = ||e||^2 + 256 (positive scores -> raw bits order-preserving),
//   key = (bits & ~63) | ct, 4-op top2. 32 rows/wave, two 16-row A-sets share
//   each B read; B tiles from L2, sequential order, compiler unroll-2.
//   Flagged rows exactly re-solved IN-WAVE (fp32, no reg array).
// np.argmin first-min tie-break preserved (ct in key LSBs + residue
//   tie-break; near-ties re-solved exactly with index-ordered selection).

#define VQ_N 262144
#define VQ_DIM 64
#define VQ_K 1024
#define NT 64                   // 64 code-tiles of 16 codes
#define TCH 128                 // 16B chunks per tile (hi only) = 2048 B
#define FLAG_EPS 0.5f

typedef short short8 __attribute__((ext_vector_type(8)));
typedef float f32x4 __attribute__((ext_vector_type(4)));

// ws layout (bytes)
#define WS_BFRAG 0                   // 64 tiles * 2048 B = 131072
#define WS_E2    (128*1024)          // float[1024] raw ||e||^2 (resolve)
#define WS_E2P   (132*1024)          // float[1024] ||e||^2 + 256 (scan init)
#define WS_NEEDED (136*1024)

static __device__ __forceinline__ unsigned short f2bf_rtne(float f) {
    unsigned u = __float_as_uint(f);
    unsigned r = u + 0x7FFFu + ((u >> 16) & 1u);
    return (unsigned short)(r >> 16);
}
static __device__ __forceinline__ float bf2f(unsigned short h) {
    return __uint_as_float(((unsigned)h) << 16);
}

// ---------------- prep: B fragments (hi only), e2 / e2+256 ----------------
// chunk t = ct*128 + kc*64 + l   (kc: K-chunk)
// content: 8 bf16 of embed[ct*16 + (l&15)][kc*32 + (l>>4)*8 + j]
__global__ void vq_prep(const float* __restrict__ embed, unsigned char* ws) {
    int t = blockIdx.x * 256 + threadIdx.x;     // 0 .. 9215
    if (t < NT * TCH) {
        int ct = t >> 7;
        int c = t & 127;
        int kc = (c >> 6) & 1;
        int l = c & 63;
        int code = ct * 16 + (l & 15);
        int kbase = kc * 32 + ((l >> 4) << 3);
        const float* ep = embed + (size_t)code * VQ_DIM + kbase;
        short8 pack;
#pragma unroll
        for (int j = 0; j < 8; ++j) pack[j] = (short)f2bf_rtne(ep[j]);
        ((short8*)(ws + WS_BFRAG))[t] = pack;
    } else if (t < NT * TCH + VQ_K) {
        int code = t - NT * TCH;
        const float* ep = embed + (size_t)code * VQ_DIM;
        float a0 = 0, a1 = 0, a2 = 0, a3 = 0;
#pragma unroll
        for (int j = 0; j < VQ_DIM; j += 4) {
            a0 = fmaf(ep[j], ep[j], a0);
            a1 = fmaf(ep[j + 1], ep[j + 1], a1);
            a2 = fmaf(ep[j + 2], ep[j + 2], a2);
            a3 = fmaf(ep[j + 3], ep[j + 3], a3);
        }
        float e2 = (a0 + a1) + (a2 + a3);
        ((float*)(ws + WS_E2))[code] = e2;
        ((float*)(ws + WS_E2P))[code] = e2 + 256.0f;
    }
}

// ---------------- stage 1: scan + gather + in-wave exact re-solve ----------------
__global__ __launch_bounds__(256, 4)
void vq_stage1(const float* __restrict__ x, const float* __restrict__ embed,
               unsigned char* ws, float* __restrict__ out) {
    __shared__ int idx_s[4][32];        // winner code per wave-row

    const int tid = threadIdx.x;
    const int lane = tid & 63;
    const int wave = tid >> 6;
    const int gwave = blockIdx.x * 4 + wave;   // owns 32 rows
    const int R0 = gwave * 32;
    const int g = lane >> 4;            // 0..3
    const int res = lane & 15;
    const int khalf = g << 3;           // A-frag k-offset within 32-chunk

    const short8* bsrc = (const short8*)(ws + WS_BFRAG);
    const float* e2g = (const float*)(ws + WS_E2);
    const float* e2p = (const float*)(ws + WS_E2P);

    // ---- A fragments: -2x hi/lo, two 16-row sets, named scalars ----
    short8 ah00, ah01, al00, al01, ah10, ah11, al10, al11;
#define MAKE_A(ROW, KC, AH, AL)                                             \
    {                                                                       \
        const float4* p4 = (const float4*)(x + (size_t)(ROW) * VQ_DIM +     \
                                           (KC) * 32 + khalf);              \
        float4 v0 = p4[0], v1 = p4[1];                                      \
        float q0 = -2.0f * v0.x, q1 = -2.0f * v0.y, q2 = -2.0f * v0.z,      \
              q3 = -2.0f * v0.w, q4 = -2.0f * v1.x, q5 = -2.0f * v1.y,      \
              q6 = -2.0f * v1.z, q7 = -2.0f * v1.w;                         \
        unsigned short h0 = f2bf_rtne(q0), h1 = f2bf_rtne(q1),              \
                       h2 = f2bf_rtne(q2), h3 = f2bf_rtne(q3),              \
                       h4 = f2bf_rtne(q4), h5 = f2bf_rtne(q5),              \
                       h6 = f2bf_rtne(q6), h7 = f2bf_rtne(q7);              \
        AH[0] = (short)h0; AH[1] = (short)h1; AH[2] = (short)h2;            \
        AH[3] = (short)h3; AH[4] = (short)h4; AH[5] = (short)h5;            \
        AH[6] = (short)h6; AH[7] = (short)h7;                               \
        AL[0] = (short)f2bf_rtne(q0 - bf2f(h0));                            \
        AL[1] = (short)f2bf_rtne(q1 - bf2f(h1));                            \
        AL[2] = (short)f2bf_rtne(q2 - bf2f(h2));                            \
        AL[3] = (short)f2bf_rtne(q3 - bf2f(h3));                            \
        AL[4] = (short)f2bf_rtne(q4 - bf2f(h4));                            \
        AL[5] = (short)f2bf_rtne(q5 - bf2f(h5));                            \
        AL[6] = (short)f2bf_rtne(q6 - bf2f(h6));                            \
        AL[7] = (short)f2bf_rtne(q7 - bf2f(h7));                            \
    }
    const int row0 = R0 + res;
    const int row1 = row0 + 16;
    MAKE_A(row0, 0, ah00, al00)
    MAKE_A(row0, 1, ah01, al01)
    MAKE_A(row1, 0, ah10, al10)
    MAKE_A(row1, 1, ah11, al11)
#undef MAKE_A

    unsigned m1k0[4], m2k0[4], m1k1[4], m2k1[4];
#pragma unroll
    for (int r = 0; r < 4; ++r) {
        m1k0[r] = 0xFFFFFFFFu; m2k0[r] = 0xFFFFFFFFu;
        m1k1[r] = 0xFFFFFFFFu; m2k1[r] = 0xFFFFFFFFu;
    }

    // ---- main scan: 2 B loads + 8 MFMA per tile, sequential, unroll-2 ----
#pragma unroll 2
    for (int ct = 0; ct < NT; ++ct) {
        const short8* bt = bsrc + (size_t)ct * TCH;
        short8 bh0 = bt[lane];
        short8 bh1 = bt[64 + lane];
        float e2c = e2p[ct * 16 + res];
        unsigned ctu = (unsigned)ct;

        f32x4 acc0 = {e2c, e2c, e2c, e2c};
        acc0 = __builtin_amdgcn_mfma_f32_16x16x32_bf16(al00, bh0, acc0, 0, 0, 0);
        acc0 = __builtin_amdgcn_mfma_f32_16x16x32_bf16(al01, bh1, acc0, 0, 0, 0);
        acc0 = __builtin_amdgcn_mfma_f32_16x16x32_bf16(ah00, bh0, acc0, 0, 0, 0);
        acc0 = __builtin_amdgcn_mfma_f32_16x16x32_bf16(ah01, bh1, acc0, 0, 0, 0);

        f32x4 acc1 = {e2c, e2c, e2c, e2c};
        acc1 = __builtin_amdgcn_mfma_f32_16x16x32_bf16(al10, bh0, acc1, 0, 0, 0);
        acc1 = __builtin_amdgcn_mfma_f32_16x16x32_bf16(al11, bh1, acc1, 0, 0, 0);
        acc1 = __builtin_amdgcn_mfma_f32_16x16x32_bf16(ah10, bh0, acc1, 0, 0, 0);
        acc1 = __builtin_amdgcn_mfma_f32_16x16x32_bf16(ah11, bh1, acc1, 0, 0, 0);

#pragma unroll
        for (int r = 0; r < 4; ++r) {
            unsigned key = (__float_as_uint(acc0[r]) & 0xFFFFFFC0u) | ctu;
            unsigned t1 = m1k0[r] > key ? m1k0[r] : key;
            m2k0[r] = m2k0[r] < t1 ? m2k0[r] : t1;
            m1k0[r] = m1k0[r] < key ? m1k0[r] : key;
        }
#pragma unroll
        for (int r = 0; r < 4; ++r) {
            unsigned key = (__float_as_uint(acc1[r]) & 0xFFFFFFC0u) | ctu;
            unsigned t1 = m1k1[r] > key ? m1k1[r] : key;
            m2k1[r] = m2k1[r] < t1 ? m2k1[r] : t1;
            m1k1[r] = m1k1[r] < key ? m1k1[r] : key;
        }
    }

    // ---- reduce over the 16 codes (lanes within each 16-group) ----
    unsigned res0[4], res1[4];
#pragma unroll
    for (int r = 0; r < 4; ++r) { res0[r] = (unsigned)res; res1[r] = res0[r]; }
#define RED_STEP(M1, M2, RES, m)                                                      \
    {                                                                                 \
        _Pragma("unroll")                                                             \
        for (int r = 0; r < 4; ++r) {                                                 \
            unsigned ok = (unsigned)__shfl_xor((int)M1[r], m);                        \
            unsigned ok2 = (unsigned)__shfl_xor((int)M2[r], m);                       \
            unsigned orr = (unsigned)__shfl_xor((int)RES[r], m);                      \
            unsigned t1 = M1[r] > ok ? M1[r] : ok;                                    \
            unsigned c2 = ok2 < t1 ? ok2 : t1;                                        \
            M2[r] = M2[r] < c2 ? M2[r] : c2;                                          \
            bool take = (ok < M1[r]) || (ok == M1[r] && orr < RES[r]);                \
            if (take) { M1[r] = ok; RES[r] = orr; }                                   \
        }                                                                             \
    }
#pragma unroll
    for (int m = 1; m <= 8; m <<= 1) {
        RED_STEP(m1k0, m2k0, res0, m)
        RED_STEP(m1k1, m2k1, res1, m)
    }
#undef RED_STEP

    // ---- lanes 0/16/32/48 publish idx + margin flags for rows 4g+0..3 ----
    unsigned fmask = 0;
    if (res == 0) {
#pragma unroll
        for (int r = 0; r < 4; ++r) {
            int rl0 = 4 * g + r;
            idx_s[wave][rl0] = (int)((m1k0[r] & 63u) * 16u + res0[r]);
            float s1 = __uint_as_float(m1k0[r] & 0xFFFFFFC0u);
            float s2 = __uint_as_float(m2k0[r] & 0xFFFFFFC0u);
            if (s2 - s1 < FLAG_EPS) fmask |= 1u << rl0;
            int rl1 = 16 + 4 * g + r;
            idx_s[wave][rl1] = (int)((m1k1[r] & 63u) * 16u + res1[r]);
            float t1f = __uint_as_float(m1k1[r] & 0xFFFFFFC0u);
            float t2f = __uint_as_float(m2k1[r] & 0xFFFFFFC0u);
            if (t2f - t1f < FLAG_EPS) fmask |= 1u << rl1;
        }
    }
    fmask |= (unsigned)__shfl_xor((int)fmask, 16);
    fmask |= (unsigned)__shfl_xor((int)fmask, 32);
    unsigned wmask = (unsigned)__shfl((int)fmask, 0);
    __syncthreads();

    // ---- gather embed[idx] -> out (2 threads per row) ----
    const int orow = tid >> 1;              // 0..127
    const int ohalf = tid & 1;
    int code = idx_s[orow >> 5][orow & 31];
    const float4* ep = (const float4*)(embed + (size_t)code * VQ_DIM) + ohalf * 8;
    float4* op = (float4*)(out + (size_t)(blockIdx.x * 128 + orow) * VQ_DIM) + ohalf * 8;
#pragma unroll
    for (int j = 0; j < 8; ++j) op[j] = ep[j];

    // ---- in-wave exact fp32 re-solve of flagged rows (~6%; no reg array) ----
    while (wmask) {
        int b = __ffs(wmask) - 1;
        wmask &= wmask - 1;
        int row = R0 + b;
        const float* xr = x + (size_t)row * VQ_DIM;
        float best = __builtin_inff();
        int bi = VQ_K;
        for (int t = 0; t < VQ_K / 64; ++t) {
            int c = t * 64 + lane;
            const float* ep2 = embed + (size_t)c * VQ_DIM;
            float a0 = 0, a1 = 0, a2 = 0, a3 = 0;
#pragma unroll
            for (int j = 0; j < VQ_DIM; j += 4) {
                a0 = fmaf(xr[j], ep2[j], a0);
                a1 = fmaf(xr[j + 1], ep2[j + 1], a1);
                a2 = fmaf(xr[j + 2], ep2[j + 2], a2);
                a3 = fmaf(xr[j + 3], ep2[j + 3], a3);
            }
            float dot = (a0 + a1) + (a2 + a3);
            float s = fmaf(-2.0f, dot, e2g[c]);
            if (s < best || (s == best && c < bi)) { best = s; bi = c; }
        }
#pragma unroll
        for (int m = 1; m <= 32; m <<= 1) {
            float ob = __shfl_xor(best, m);
            int oi = __shfl_xor(bi, m);
            if (ob < best || (ob == best && oi < bi)) { best = ob; bi = oi; }
        }
        out[(size_t)row * VQ_DIM + lane] = embed[(size_t)bi * VQ_DIM + lane];
    }
}

// ---------------- fallback (round-1 fp32, only if ws too small) ----------------
__global__ __launch_bounds__(256, 4)
void vq_fallback(const float* __restrict__ x, const float* __restrict__ embed,
                 float* __restrict__ out) {
    __shared__ float e2s[VQ_K];
    const int tid = threadIdx.x;
    for (int c = tid; c < VQ_K; c += 256) {
        const float4* ep = (const float4*)(embed + c * VQ_DIM);
        float s = 0.0f;
#pragma unroll
        for (int j = 0; j < VQ_DIM / 4; ++j) {
            float4 v = ep[j];
            s = fmaf(v.x, v.x, s); s = fmaf(v.y, v.y, s);
            s = fmaf(v.z, v.z, s); s = fmaf(v.w, v.w, s);
        }
        e2s[c] = s;
    }
    __syncthreads();
    const int row = blockIdx.x * 256 + tid;
    float xr[VQ_DIM];
    const float4* xp = (const float4*)(x + (size_t)row * VQ_DIM);
#pragma unroll
    for (int j = 0; j < VQ_DIM / 4; ++j) {
        float4 v = xp[j];
        xr[4 * j] = v.x; xr[4 * j + 1] = v.y; xr[4 * j + 2] = v.z; xr[4 * j + 3] = v.w;
    }
    float best = __builtin_inff();
    int bidx = 0;
    for (int c = 0; c < VQ_K; ++c) {
        const float4* ep = (const float4*)(embed + c * VQ_DIM);
        float a0 = 0, a1 = 0, a2 = 0, a3 = 0;
#pragma unroll
        for (int j = 0; j < VQ_DIM / 4; ++j) {
            float4 v = ep[j];
            a0 = fmaf(xr[4 * j], v.x, a0);
            a1 = fmaf(xr[4 * j + 1], v.y, a1);
            a2 = fmaf(xr[4 * j + 2], v.z, a2);
            a3 = fmaf(xr[4 * j + 3], v.w, a3);
        }
        float score = fmaf(-2.0f, (a0 + a1) + (a2 + a3), e2s[c]);
        if (score < best) { best = score; bidx = c; }
    }
    const float4* bp = (const float4*)(embed + (size_t)bidx * VQ_DIM);
    float4* op = (float4*)(out + (size_t)row * VQ_DIM);
#pragma unroll
    for (int j = 0; j < VQ_DIM / 4; ++j) op[j] = bp[j];
}

extern "C" void kernel_launch(void* const* d_in, const int* in_sizes, int n_in,
                              void* d_out, int out_size, void* d_ws, size_t ws_size,
                              hipStream_t stream) {
    const float* x = (const float*)d_in[0];
    const float* embed = (const float*)d_in[1];
    float* out = (float*)d_out;
    if (ws_size < WS_NEEDED) {
        hipLaunchKernelGGL(vq_fallback, dim3(VQ_N / 256), dim3(256), 0, stream, x, embed, out);
        return;
    }
    unsigned char* ws = (unsigned char*)d_ws;
    hipLaunchKernelGGL(vq_prep, dim3(36), dim3(256), 0, stream, embed, ws);
    hipLaunchKernelGGL(vq_stage1, dim3(VQ_N / 128), dim3(256), 0, stream, x, embed, ws, out);
}

// Round 13
// 275.650 us; speedup vs baseline: 3.9846x; 3.9846x over previous
//
#include <hip/hip_runtime.h>

// VQ: N=262144 rows, DIM=64, K=1024 codes.
// Stage 1 (fast scan): 16x16x32 bf16 MFMA, TWO-product split
//   score = -2*(xh+xl).eh + ||e||^2 + 256 (B = bf16(e) hi only).
//   err = -2 sum x_i*el_i, sigma ~1.9e-2; margin >= EPS1=0.32 provably keeps
//   the true argmin. Rows with margin < EPS1 (~4%) appended (atomic) to a
//   compacted list. Masked-key top2 (key = bits&~63 | ct), 32 rows/wave.
// Stage 2 (batch re-solve): each active wave takes 32 listed rows and runs the
//   R6-proven THREE-product scan (err ~1e-3), eps2 = 1.2e-2; its own near-ties
//   (~0.1% of list) are exact-resolved fp32 serially in-wave.
// np.argmin first-min tie-break preserved at every level.

#define VQ_N 262144
#define VQ_DIM 64
#define VQ_K 1024
#define NT 64                   // 64 code-tiles of 16 codes
#define TCH 128                 // 16B chunks per hi (or lo) tile = 2048 B
#define EPS1 0.32f
#define EPS2 1.2e-2f
#define LIST_CAP 32768

typedef short short8 __attribute__((ext_vector_type(8)));
typedef float f32x4 __attribute__((ext_vector_type(4)));

// ws layout (bytes)
#define WS_BH    0                   // 64 tiles * 2048 B = 131072 (e hi)
#define WS_BL    (128*1024)          // 131072 (e lo)
#define WS_E2    (256*1024)          // float[1024] raw ||e||^2
#define WS_CNT   (260*1024)          // unsigned count
#define WS_LIST  (261*1024)          // int[LIST_CAP] flagged rows (128 KB)
#define WS_NEEDED (392*1024)

static __device__ __forceinline__ unsigned short f2bf_rtne(float f) {
    unsigned u = __float_as_uint(f);
    unsigned r = u + 0x7FFFu + ((u >> 16) & 1u);
    return (unsigned short)(r >> 16);
}
static __device__ __forceinline__ float bf2f(unsigned short h) {
    return __uint_as_float(((unsigned)h) << 16);
}

// ---------------- prep ----------------
// BH chunk t = ct*128 + kc*64 + l : 8 bf16 of embed[ct*16+(l&15)][kc*32+(l>>4)*8+j]
__global__ void vq_prep(const float* __restrict__ embed, unsigned char* ws) {
    int t = blockIdx.x * 256 + threadIdx.x;     // 0 .. 17919
    if (t < 16384) {
        int arr = t >> 13;                      // 0 = hi, 1 = lo
        int c = t & 8191;
        int ct = c >> 7;
        int kc = (c >> 6) & 1;
        int l = c & 63;
        int code = ct * 16 + (l & 15);
        int kbase = kc * 32 + ((l >> 4) << 3);
        const float* ep = embed + (size_t)code * VQ_DIM + kbase;
        short8 pack;
#pragma unroll
        for (int j = 0; j < 8; ++j) {
            float v = ep[j];
            unsigned short h = f2bf_rtne(v);
            pack[j] = arr ? (short)f2bf_rtne(v - bf2f(h)) : (short)h;
        }
        ((short8*)(ws + (arr ? WS_BL : WS_BH)))[c] = pack;
    } else if (t < 16384 + VQ_K) {
        int code = t - 16384;
        const float* ep = embed + (size_t)code * VQ_DIM;
        float a0 = 0, a1 = 0, a2 = 0, a3 = 0;
#pragma unroll
        for (int j = 0; j < VQ_DIM; j += 4) {
            a0 = fmaf(ep[j], ep[j], a0);
            a1 = fmaf(ep[j + 1], ep[j + 1], a1);
            a2 = fmaf(ep[j + 2], ep[j + 2], a2);
            a3 = fmaf(ep[j + 3], ep[j + 3], a3);
        }
        ((float*)(ws + WS_E2))[code] = (a0 + a1) + (a2 + a3);
    } else if (t == 16384 + VQ_K) {
        *(unsigned*)(ws + WS_CNT) = 0u;
    }
}

// ---- shared helpers (macros) ----
#define MAKE_A(ROW, KC, AH, AL)                                             \
    {                                                                       \
        const float4* p4 = (const float4*)(x + (size_t)(ROW) * VQ_DIM +     \
                                           (KC) * 32 + khalf);              \
        float4 v0 = p4[0], v1 = p4[1];                                      \
        float q0 = -2.0f * v0.x, q1 = -2.0f * v0.y, q2 = -2.0f * v0.z,      \
              q3 = -2.0f * v0.w, q4 = -2.0f * v1.x, q5 = -2.0f * v1.y,      \
              q6 = -2.0f * v1.z, q7 = -2.0f * v1.w;                         \
        unsigned short h0 = f2bf_rtne(q0), h1 = f2bf_rtne(q1),              \
                       h2 = f2bf_rtne(q2), h3 = f2bf_rtne(q3),              \
                       h4 = f2bf_rtne(q4), h5 = f2bf_rtne(q5),              \
                       h6 = f2bf_rtne(q6), h7 = f2bf_rtne(q7);              \
        AH[0] = (short)h0; AH[1] = (short)h1; AH[2] = (short)h2;            \
        AH[3] = (short)h3; AH[4] = (short)h4; AH[5] = (short)h5;            \
        AH[6] = (short)h6; AH[7] = (short)h7;                               \
        AL[0] = (short)f2bf_rtne(q0 - bf2f(h0));                            \
        AL[1] = (short)f2bf_rtne(q1 - bf2f(h1));                            \
        AL[2] = (short)f2bf_rtne(q2 - bf2f(h2));                            \
        AL[3] = (short)f2bf_rtne(q3 - bf2f(h3));                            \
        AL[4] = (short)f2bf_rtne(q4 - bf2f(h4));                            \
        AL[5] = (short)f2bf_rtne(q5 - bf2f(h5));                            \
        AL[6] = (short)f2bf_rtne(q6 - bf2f(h6));                            \
        AL[7] = (short)f2bf_rtne(q7 - bf2f(h7));                            \
    }

#define KEYUPD(ACC, M1, M2, CTU)                                                      \
        _Pragma("unroll")                                                             \
        for (int r = 0; r < 4; ++r) {                                                 \
            unsigned key = (__float_as_uint(ACC[r]) & 0xFFFFFFC0u) | (CTU);           \
            unsigned t1 = M1[r] > key ? M1[r] : key;                                  \
            M2[r] = M2[r] < t1 ? M2[r] : t1;                                          \
            M1[r] = M1[r] < key ? M1[r] : key;                                        \
        }

#define RED_STEP(M1, M2, RES, m)                                                      \
    {                                                                                 \
        _Pragma("unroll")                                                             \
        for (int r = 0; r < 4; ++r) {                                                 \
            unsigned ok = (unsigned)__shfl_xor((int)M1[r], m);                        \
            unsigned ok2 = (unsigned)__shfl_xor((int)M2[r], m);                       \
            unsigned orr = (unsigned)__shfl_xor((int)RES[r], m);                      \
            unsigned t1 = M1[r] > ok ? M1[r] : ok;                                    \
            unsigned c2 = ok2 < t1 ? ok2 : t1;                                        \
            M2[r] = M2[r] < c2 ? M2[r] : c2;                                          \
            bool take = (ok < M1[r]) || (ok == M1[r] && orr < RES[r]);                \
            if (take) { M1[r] = ok; RES[r] = orr; }                                   \
        }                                                                             \
    }

// serial exact fp32 re-solve of one row by a full wave
#define EXACT_ROW(ROW)                                                                \
    {                                                                                 \
        const float* xr = x + (size_t)(ROW) * VQ_DIM;                                 \
        float best = __builtin_inff();                                                \
        int bi = VQ_K;                                                                \
        for (int t = 0; t < VQ_K / 64; ++t) {                                         \
            int c = t * 64 + lane;                                                    \
            const float* ep2 = embed + (size_t)c * VQ_DIM;                            \
            float a0 = 0, a1 = 0, a2 = 0, a3 = 0;                                     \
            _Pragma("unroll")                                                         \
            for (int j = 0; j < VQ_DIM; j += 4) {                                     \
                a0 = fmaf(xr[j], ep2[j], a0);                                         \
                a1 = fmaf(xr[j + 1], ep2[j + 1], a1);                                 \
                a2 = fmaf(xr[j + 2], ep2[j + 2], a2);                                 \
                a3 = fmaf(xr[j + 3], ep2[j + 3], a3);                                 \
            }                                                                         \
            float dot = (a0 + a1) + (a2 + a3);                                        \
            float s = fmaf(-2.0f, dot, e2g[c]);                                       \
            if (s < best || (s == best && c < bi)) { best = s; bi = c; }              \
        }                                                                             \
        _Pragma("unroll")                                                             \
        for (int m = 1; m <= 32; m <<= 1) {                                           \
            float ob = __shfl_xor(best, m);                                           \
            int oi = __shfl_xor(bi, m);                                               \
            if (ob < best || (ob == best && oi < bi)) { best = ob; bi = oi; }         \
        }                                                                             \
        out[(size_t)(ROW) * VQ_DIM + lane] = embed[(size_t)bi * VQ_DIM + lane];       \
    }

// ---------------- stage 1: two-product scan + gather + list append ----------------
__global__ __launch_bounds__(256, 4)
void vq_stage1(const float* __restrict__ x, const float* __restrict__ embed,
               unsigned char* ws, float* __restrict__ out) {
    __shared__ int idx_s[4][32];

    const int tid = threadIdx.x;
    const int lane = tid & 63;
    const int wave = tid >> 6;
    const int gwave = blockIdx.x * 4 + wave;   // owns 32 rows
    const int R0 = gwave * 32;
    const int g = lane >> 4;
    const int res = lane & 15;
    const int khalf = g << 3;

    const short8* bsrc = (const short8*)(ws + WS_BH);
    const float* e2g = (const float*)(ws + WS_E2);
    unsigned* cnt = (unsigned*)(ws + WS_CNT);
    int* list = (int*)(ws + WS_LIST);

    short8 ah00, ah01, al00, al01, ah10, ah11, al10, al11;
    const int row0 = R0 + res;
    const int row1 = row0 + 16;
    MAKE_A(row0, 0, ah00, al00)
    MAKE_A(row0, 1, ah01, al01)
    MAKE_A(row1, 0, ah10, al10)
    MAKE_A(row1, 1, ah11, al11)

    unsigned m1k0[4], m2k0[4], m1k1[4], m2k1[4];
#pragma unroll
    for (int r = 0; r < 4; ++r) {
        m1k0[r] = 0xFFFFFFFFu; m2k0[r] = 0xFFFFFFFFu;
        m1k1[r] = 0xFFFFFFFFu; m2k1[r] = 0xFFFFFFFFu;
    }

#pragma unroll 2
    for (int ct = 0; ct < NT; ++ct) {
        const short8* bt = bsrc + (size_t)ct * TCH;
        short8 bh0 = bt[lane];
        short8 bh1 = bt[64 + lane];
        float e2c = e2g[ct * 16 + res] + 256.0f;
        unsigned ctu = (unsigned)ct;

        f32x4 acc0 = {e2c, e2c, e2c, e2c};
        acc0 = __builtin_amdgcn_mfma_f32_16x16x32_bf16(al00, bh0, acc0, 0, 0, 0);
        acc0 = __builtin_amdgcn_mfma_f32_16x16x32_bf16(al01, bh1, acc0, 0, 0, 0);
        acc0 = __builtin_amdgcn_mfma_f32_16x16x32_bf16(ah00, bh0, acc0, 0, 0, 0);
        acc0 = __builtin_amdgcn_mfma_f32_16x16x32_bf16(ah01, bh1, acc0, 0, 0, 0);

        f32x4 acc1 = {e2c, e2c, e2c, e2c};
        acc1 = __builtin_amdgcn_mfma_f32_16x16x32_bf16(al10, bh0, acc1, 0, 0, 0);
        acc1 = __builtin_amdgcn_mfma_f32_16x16x32_bf16(al11, bh1, acc1, 0, 0, 0);
        acc1 = __builtin_amdgcn_mfma_f32_16x16x32_bf16(ah10, bh0, acc1, 0, 0, 0);
        acc1 = __builtin_amdgcn_mfma_f32_16x16x32_bf16(ah11, bh1, acc1, 0, 0, 0);

        KEYUPD(acc0, m1k0, m2k0, ctu)
        KEYUPD(acc1, m1k1, m2k1, ctu)
    }

    unsigned res0[4], res1[4];
#pragma unroll
    for (int r = 0; r < 4; ++r) { res0[r] = (unsigned)res; res1[r] = res0[r]; }
#pragma unroll
    for (int m = 1; m <= 8; m <<= 1) {
        RED_STEP(m1k0, m2k0, res0, m)
        RED_STEP(m1k1, m2k1, res1, m)
    }

    unsigned fmask = 0;
    if (res == 0) {
#pragma unroll
        for (int r = 0; r < 4; ++r) {
            int rl0 = 4 * g + r;
            idx_s[wave][rl0] = (int)((m1k0[r] & 63u) * 16u + res0[r]);
            float s1 = __uint_as_float(m1k0[r] & 0xFFFFFFC0u);
            float s2 = __uint_as_float(m2k0[r] & 0xFFFFFFC0u);
            if (s2 - s1 < EPS1) fmask |= 1u << rl0;
            int rl1 = 16 + 4 * g + r;
            idx_s[wave][rl1] = (int)((m1k1[r] & 63u) * 16u + res1[r]);
            float t1f = __uint_as_float(m1k1[r] & 0xFFFFFFC0u);
            float t2f = __uint_as_float(m2k1[r] & 0xFFFFFFC0u);
            if (t2f - t1f < EPS1) fmask |= 1u << rl1;
        }
    }
    fmask |= (unsigned)__shfl_xor((int)fmask, 16);
    fmask |= (unsigned)__shfl_xor((int)fmask, 32);

    // lane 0: append flagged rows to the global list (overflow -> omask)
    unsigned omask = 0;
    if (lane == 0 && fmask) {
        int n = __popc(fmask);
        unsigned pos = atomicAdd(cnt, (unsigned)n);
        unsigned m = fmask;
        int i = 0;
        while (m) {
            int b = __ffs(m) - 1;
            m &= m - 1;
            if (pos + (unsigned)i < LIST_CAP) list[pos + i] = R0 + b;
            else omask |= 1u << b;
            ++i;
        }
    }
    omask = (unsigned)__shfl((int)omask, 0);
    __syncthreads();

    // gather embed[idx] -> out (2 threads per row)
    const int orow = tid >> 1;
    const int ohalf = tid & 1;
    int code = idx_s[orow >> 5][orow & 31];
    const float4* ep = (const float4*)(embed + (size_t)code * VQ_DIM) + ohalf * 8;
    float4* op = (float4*)(out + (size_t)(blockIdx.x * 128 + orow) * VQ_DIM) + ohalf * 8;
#pragma unroll
    for (int j = 0; j < 8; ++j) op[j] = ep[j];

    // overflow safety net (expected never)
    while (omask) {
        int b = __ffs(omask) - 1;
        omask &= omask - 1;
        EXACT_ROW(R0 + b)
    }
}

// ---------------- stage 2: 3-product MFMA re-solve of listed rows ----------------
__global__ __launch_bounds__(256, 4)
void vq_stage2(const float* __restrict__ x, const float* __restrict__ embed,
               unsigned char* ws, float* __restrict__ out) {
    const int tid = threadIdx.x;
    const int lane = tid & 63;
    const int wave = tid >> 6;
    const int w = blockIdx.x * 4 + wave;

    const unsigned* cnt = (const unsigned*)(ws + WS_CNT);
    const int* list = (const int*)(ws + WS_LIST);
    const short8* bh = (const short8*)(ws + WS_BH);
    const short8* bl = (const short8*)(ws + WS_BL);
    const float* e2g = (const float*)(ws + WS_E2);

    int n = (int)*cnt;
    n = n < LIST_CAP ? n : LIST_CAP;
    int nw = (n + 31) >> 5;
    if (w >= nw) return;

    const int base = w * 32;
    const int g = lane >> 4;
    const int res = lane & 15;
    const int khalf = g << 3;

    // gathered rows for the two 16-row A-sets
    const int i0 = base + res;
    const int i1 = base + 16 + res;
    const int row0 = list[i0 < n ? i0 : n - 1];
    const int row1 = list[i1 < n ? i1 : n - 1];

    short8 ah00, ah01, al00, al01, ah10, ah11, al10, al11;
    MAKE_A(row0, 0, ah00, al00)
    MAKE_A(row0, 1, ah01, al01)
    MAKE_A(row1, 0, ah10, al10)
    MAKE_A(row1, 1, ah11, al11)

    unsigned m1k0[4], m2k0[4], m1k1[4], m2k1[4];
#pragma unroll
    for (int r = 0; r < 4; ++r) {
        m1k0[r] = 0xFFFFFFFFu; m2k0[r] = 0xFFFFFFFFu;
        m1k1[r] = 0xFFFFFFFFu; m2k1[r] = 0xFFFFFFFFu;
    }

#pragma unroll 2
    for (int ct = 0; ct < NT; ++ct) {
        const short8* bht = bh + (size_t)ct * TCH;
        const short8* blt = bl + (size_t)ct * TCH;
        short8 bh0 = bht[lane];
        short8 bh1 = bht[64 + lane];
        short8 bl0 = blt[lane];
        short8 bl1 = blt[64 + lane];
        float e2c = e2g[ct * 16 + res] + 256.0f;
        unsigned ctu = (unsigned)ct;

        f32x4 acc0 = {e2c, e2c, e2c, e2c};
        acc0 = __builtin_amdgcn_mfma_f32_16x16x32_bf16(al00, bh0, acc0, 0, 0, 0);
        acc0 = __builtin_amdgcn_mfma_f32_16x16x32_bf16(al01, bh1, acc0, 0, 0, 0);
        acc0 = __builtin_amdgcn_mfma_f32_16x16x32_bf16(ah00, bl0, acc0, 0, 0, 0);
        acc0 = __builtin_amdgcn_mfma_f32_16x16x32_bf16(ah01, bl1, acc0, 0, 0, 0);
        acc0 = __builtin_amdgcn_mfma_f32_16x16x32_bf16(ah00, bh0, acc0, 0, 0, 0);
        acc0 = __builtin_amdgcn_mfma_f32_16x16x32_bf16(ah01, bh1, acc0, 0, 0, 0);

        f32x4 acc1 = {e2c, e2c, e2c, e2c};
        acc1 = __builtin_amdgcn_mfma_f32_16x16x32_bf16(al10, bh0, acc1, 0, 0, 0);
        acc1 = __builtin_amdgcn_mfma_f32_16x16x32_bf16(al11, bh1, acc1, 0, 0, 0);
        acc1 = __builtin_amdgcn_mfma_f32_16x16x32_bf16(ah10, bl0, acc1, 0, 0, 0);
        acc1 = __builtin_amdgcn_mfma_f32_16x16x32_bf16(ah11, bl1, acc1, 0, 0, 0);
        acc1 = __builtin_amdgcn_mfma_f32_16x16x32_bf16(ah10, bh0, acc1, 0, 0, 0);
        acc1 = __builtin_amdgcn_mfma_f32_16x16x32_bf16(ah11, bh1, acc1, 0, 0, 0);

        KEYUPD(acc0, m1k0, m2k0, ctu)
        KEYUPD(acc1, m1k1, m2k1, ctu)
    }

    unsigned res0[4], res1[4];
#pragma unroll
    for (int r = 0; r < 4; ++r) { res0[r] = (unsigned)res; res1[r] = res0[r]; }
#pragma unroll
    for (int m = 1; m <= 8; m <<= 1) {
        RED_STEP(m1k0, m2k0, res0, m)
        RED_STEP(m1k1, m2k1, res1, m)
    }

    // winner codes + near-tie mask (bit p over the 32 gathered rows)
    int code0[4], code1[4];
    unsigned fmask = 0;
#pragma unroll
    for (int r = 0; r < 4; ++r) {
        code0[r] = (int)((m1k0[r] & 63u) * 16u + res0[r]);
        code1[r] = (int)((m1k1[r] & 63u) * 16u + res1[r]);
        float s1a = __uint_as_float(m1k0[r] & 0xFFFFFFC0u);
        float s2a = __uint_as_float(m2k0[r] & 0xFFFFFFC0u);
        if (s2a - s1a < EPS2) fmask |= 1u << (4 * g + r);
        float s1b = __uint_as_float(m1k1[r] & 0xFFFFFFC0u);
        float s2b = __uint_as_float(m2k1[r] & 0xFFFFFFC0u);
        if (s2b - s1b < EPS2) fmask |= 1u << (16 + 4 * g + r);
    }
    fmask |= (unsigned)__shfl_xor((int)fmask, 16);
    fmask |= (unsigned)__shfl_xor((int)fmask, 32);
    unsigned wmask = (unsigned)__shfl((int)fmask, 0);

    // gather-write winners: lane handles q = lane>>1, half = lane&1
    {
        const int q = lane >> 1;
        const int iq = base + q;
        const int rowq = list[iq < n ? iq : n - 1];
        const int setq = q >> 4;
        const int gq = (q & 15) >> 2;
        const int rq = q & 3;
        const int src = gq << 4;
        int a0 = __shfl(code0[0], src), a1 = __shfl(code0[1], src);
        int a2 = __shfl(code0[2], src), a3 = __shfl(code0[3], src);
        int b0 = __shfl(code1[0], src), b1 = __shfl(code1[1], src);
        int b2 = __shfl(code1[2], src), b3 = __shfl(code1[3], src);
        int cs0 = (rq == 0) ? a0 : (rq == 1) ? a1 : (rq == 2) ? a2 : a3;
        int cs1 = (rq == 0) ? b0 : (rq == 1) ? b1 : (rq == 2) ? b2 : b3;
        int my = setq ? cs1 : cs0;
        const float4* ep = (const float4*)(embed + (size_t)my * VQ_DIM) + (lane & 1) * 8;
        float4* op = (float4*)(out + (size_t)rowq * VQ_DIM) + (lane & 1) * 8;
#pragma unroll
        for (int j = 0; j < 8; ++j) op[j] = ep[j];
    }

    // exact fp32 re-solve of this wave's near-ties (rare)
    while (wmask) {
        int b = __ffs(wmask) - 1;
        wmask &= wmask - 1;
        int ib = base + b;
        int row = list[ib < n ? ib : n - 1];
        EXACT_ROW(row)
    }
}

// ---------------- fallback (round-1 fp32, only if ws too small) ----------------
__global__ __launch_bounds__(256, 4)
void vq_fallback(const float* __restrict__ x, const float* __restrict__ embed,
                 float* __restrict__ out) {
    __shared__ float e2s[VQ_K];
    const int tid = threadIdx.x;
    for (int c = tid; c < VQ_K; c += 256) {
        const float4* ep = (const float4*)(embed + c * VQ_DIM);
        float s = 0.0f;
#pragma unroll
        for (int j = 0; j < VQ_DIM / 4; ++j) {
            float4 v = ep[j];
            s = fmaf(v.x, v.x, s); s = fmaf(v.y, v.y, s);
            s = fmaf(v.z, v.z, s); s = fmaf(v.w, v.w, s);
        }
        e2s[c] = s;
    }
    __syncthreads();
    const int row = blockIdx.x * 256 + tid;
    float xr[VQ_DIM];
    const float4* xp = (const float4*)(x + (size_t)row * VQ_DIM);
#pragma unroll
    for (int j = 0; j < VQ_DIM / 4; ++j) {
        float4 v = xp[j];
        xr[4 * j] = v.x; xr[4 * j + 1] = v.y; xr[4 * j + 2] = v.z; xr[4 * j + 3] = v.w;
    }
    float best = __builtin_inff();
    int bidx = 0;
    for (int c = 0; c < VQ_K; ++c) {
        const float4* ep = (const float4*)(embed + c * VQ_DIM);
        float a0 = 0, a1 = 0, a2 = 0, a3 = 0;
#pragma unroll
        for (int j = 0; j < VQ_DIM / 4; ++j) {
            float4 v = ep[j];
            a0 = fmaf(xr[4 * j], v.x, a0);
            a1 = fmaf(xr[4 * j + 1], v.y, a1);
            a2 = fmaf(xr[4 * j + 2], v.z, a2);
            a3 = fmaf(xr[4 * j + 3], v.w, a3);
        }
        float score = fmaf(-2.0f, (a0 + a1) + (a2 + a3), e2s[c]);
        if (score < best) { best = score; bidx = c; }
    }
    const float4* bp = (const float4*)(embed + (size_t)bidx * VQ_DIM);
    float4* op = (float4*)(out + (size_t)row * VQ_DIM);
#pragma unroll
    for (int j = 0; j < VQ_DIM / 4; ++j) op[j] = bp[j];
}

extern "C" void kernel_launch(void* const* d_in, const int* in_sizes, int n_in,
                              void* d_out, int out_size, void* d_ws, size_t ws_size,
                              hipStream_t stream) {
    const float* x = (const float*)d_in[0];
    const float* embed = (const float*)d_in[1];
    float* out = (float*)d_out;
    if (ws_size < WS_NEEDED) {
        hipLaunchKernelGGL(vq_fallback, dim3(VQ_N / 256), dim3(256), 0, stream, x, embed, out);
        return;
    }
    unsigned char* ws = (unsigned char*)d_ws;
    hipLaunchKernelGGL(vq_prep, dim3(70), dim3(256), 0, stream, embed, ws);
    hipLaunchKernelGGL(vq_stage1, dim3(VQ_N / 128), dim3(256), 0, stream, x, embed, ws, out);
    hipLaunchKernelGGL(vq_stage2, dim3(VQ_N / 128), dim3(256), 0, stream, x, embed, ws, out);
}

// Round 14
// 210.061 us; speedup vs baseline: 5.2287x; 1.3122x over previous
//
#include <hip/hip_runtime.h>

// VQ: N=262144 rows, DIM=64, K=1024 codes. Three-tier design:
// Stage 1 (fast scan, ~70us): 16x16x32 bf16 MFMA, TWO-product split
//   score = -2*(xh+xl).eh + ||e||^2 + 256 (B = bf16(e) hi only).
//   Rows with top2 margin < EPS1=0.32 (~7%) appended to list1 (1 atomic/wave).
// Stage 2 (batch refine): waves take 32 list1 rows each, THREE-product scan
//   (err ~2e-3); margin < EPS2=1.2e-2 rows (~4% of list1) appended to list2.
// Stage 3 (exact): fp32 full re-solve, ONE row per wave, grid-stride over
//   list2 (~700 rows), float4 loads. Fully parallel, no serial tails.
// np.argmin first-min tie-break preserved at every tier (ct packed in key
//   LSBs + residue tie-break; exact tier uses index-ordered selection).

#define VQ_N 262144
#define VQ_DIM 64
#define VQ_K 1024
#define NT 64                   // 64 code-tiles of 16 codes
#define TCH 128                 // 16B chunks per hi (or lo) tile = 2048 B
#define EPS1 0.32f
#define EPS2 1.2e-2f
#define LIST_CAP 32768
#define LIST2_CAP 8192
#define NWAVES_S3 8192

typedef short short8 __attribute__((ext_vector_type(8)));
typedef float f32x4 __attribute__((ext_vector_type(4)));

// ws layout (bytes)
#define WS_BH    0                   // 131072 (e hi fragments)
#define WS_BL    (128*1024)          // 131072 (e lo fragments)
#define WS_E2    (256*1024)          // float[1024] raw ||e||^2
#define WS_CNT   (260*1024)          // unsigned count (list1)
#define WS_CNT2  (260*1024 + 64)     // unsigned count (list2)
#define WS_LIST  (261*1024)          // int[LIST_CAP]  (128 KB)
#define WS_LIST2 (389*1024)          // int[LIST2_CAP] (32 KB)
#define WS_NEEDED (424*1024)

static __device__ __forceinline__ unsigned short f2bf_rtne(float f) {
    unsigned u = __float_as_uint(f);
    unsigned r = u + 0x7FFFu + ((u >> 16) & 1u);
    return (unsigned short)(r >> 16);
}
static __device__ __forceinline__ float bf2f(unsigned short h) {
    return __uint_as_float(((unsigned)h) << 16);
}

// ---------------- prep ----------------
__global__ void vq_prep(const float* __restrict__ embed, unsigned char* ws) {
    int t = blockIdx.x * 256 + threadIdx.x;     // 0 .. 17919
    if (t < 16384) {
        int arr = t >> 13;                      // 0 = hi, 1 = lo
        int c = t & 8191;
        int ct = c >> 7;
        int kc = (c >> 6) & 1;
        int l = c & 63;
        int code = ct * 16 + (l & 15);
        int kbase = kc * 32 + ((l >> 4) << 3);
        const float* ep = embed + (size_t)code * VQ_DIM + kbase;
        short8 pack;
#pragma unroll
        for (int j = 0; j < 8; ++j) {
            float v = ep[j];
            unsigned short h = f2bf_rtne(v);
            pack[j] = arr ? (short)f2bf_rtne(v - bf2f(h)) : (short)h;
        }
        ((short8*)(ws + (arr ? WS_BL : WS_BH)))[c] = pack;
    } else if (t < 16384 + VQ_K) {
        int code = t - 16384;
        const float* ep = embed + (size_t)code * VQ_DIM;
        float a0 = 0, a1 = 0, a2 = 0, a3 = 0;
#pragma unroll
        for (int j = 0; j < VQ_DIM; j += 4) {
            a0 = fmaf(ep[j], ep[j], a0);
            a1 = fmaf(ep[j + 1], ep[j + 1], a1);
            a2 = fmaf(ep[j + 2], ep[j + 2], a2);
            a3 = fmaf(ep[j + 3], ep[j + 3], a3);
        }
        ((float*)(ws + WS_E2))[code] = (a0 + a1) + (a2 + a3);
    } else if (t == 16384 + VQ_K) {
        *(unsigned*)(ws + WS_CNT) = 0u;
        *(unsigned*)(ws + WS_CNT2) = 0u;
    }
}

// ---- shared helpers ----
#define MAKE_A(ROW, KC, AH, AL)                                             \
    {                                                                       \
        const float4* p4 = (const float4*)(x + (size_t)(ROW) * VQ_DIM +     \
                                           (KC) * 32 + khalf);              \
        float4 v0 = p4[0], v1 = p4[1];                                      \
        float q0 = -2.0f * v0.x, q1 = -2.0f * v0.y, q2 = -2.0f * v0.z,      \
              q3 = -2.0f * v0.w, q4 = -2.0f * v1.x, q5 = -2.0f * v1.y,      \
              q6 = -2.0f * v1.z, q7 = -2.0f * v1.w;                         \
        unsigned short h0 = f2bf_rtne(q0), h1 = f2bf_rtne(q1),              \
                       h2 = f2bf_rtne(q2), h3 = f2bf_rtne(q3),              \
                       h4 = f2bf_rtne(q4), h5 = f2bf_rtne(q5),              \
                       h6 = f2bf_rtne(q6), h7 = f2bf_rtne(q7);              \
        AH[0] = (short)h0; AH[1] = (short)h1; AH[2] = (short)h2;            \
        AH[3] = (short)h3; AH[4] = (short)h4; AH[5] = (short)h5;            \
        AH[6] = (short)h6; AH[7] = (short)h7;                               \
        AL[0] = (short)f2bf_rtne(q0 - bf2f(h0));                            \
        AL[1] = (short)f2bf_rtne(q1 - bf2f(h1));                            \
        AL[2] = (short)f2bf_rtne(q2 - bf2f(h2));                            \
        AL[3] = (short)f2bf_rtne(q3 - bf2f(h3));                            \
        AL[4] = (short)f2bf_rtne(q4 - bf2f(h4));                            \
        AL[5] = (short)f2bf_rtne(q5 - bf2f(h5));                            \
        AL[6] = (short)f2bf_rtne(q6 - bf2f(h6));                            \
        AL[7] = (short)f2bf_rtne(q7 - bf2f(h7));                            \
    }

#define KEYUPD(ACC, M1, M2, CTU)                                                      \
        _Pragma("unroll")                                                             \
        for (int r = 0; r < 4; ++r) {                                                 \
            unsigned key = (__float_as_uint(ACC[r]) & 0xFFFFFFC0u) | (CTU);           \
            unsigned t1 = M1[r] > key ? M1[r] : key;                                  \
            M2[r] = M2[r] < t1 ? M2[r] : t1;                                          \
            M1[r] = M1[r] < key ? M1[r] : key;                                        \
        }

#define RED_STEP(M1, M2, RES, m)                                                      \
    {                                                                                 \
        _Pragma("unroll")                                                             \
        for (int r = 0; r < 4; ++r) {                                                 \
            unsigned ok = (unsigned)__shfl_xor((int)M1[r], m);                        \
            unsigned ok2 = (unsigned)__shfl_xor((int)M2[r], m);                       \
            unsigned orr = (unsigned)__shfl_xor((int)RES[r], m);                      \
            unsigned t1 = M1[r] > ok ? M1[r] : ok;                                    \
            unsigned c2 = ok2 < t1 ? ok2 : t1;                                        \
            M2[r] = M2[r] < c2 ? M2[r] : c2;                                          \
            bool take = (ok < M1[r]) || (ok == M1[r] && orr < RES[r]);                \
            if (take) { M1[r] = ok; RES[r] = orr; }                                   \
        }                                                                             \
    }

// exact fp32 re-solve of one row by a full wave (float4 loads)
#define EXACT_ROW(ROW)                                                                \
    {                                                                                 \
        const float4* xr4 = (const float4*)(x + (size_t)(ROW) * VQ_DIM);              \
        float best = __builtin_inff();                                                \
        int bi = VQ_K;                                                                \
        for (int t = 0; t < VQ_K / 64; ++t) {                                         \
            int c = t * 64 + lane;                                                    \
            const float4* ep4 = (const float4*)(embed + (size_t)c * VQ_DIM);          \
            float a0 = 0, a1 = 0, a2 = 0, a3 = 0;                                     \
            _Pragma("unroll")                                                         \
            for (int j = 0; j < VQ_DIM / 4; ++j) {                                    \
                float4 xv = xr4[j];                                                   \
                float4 ev = ep4[j];                                                   \
                a0 = fmaf(xv.x, ev.x, a0);                                            \
                a1 = fmaf(xv.y, ev.y, a1);                                            \
                a2 = fmaf(xv.z, ev.z, a2);                                            \
                a3 = fmaf(xv.w, ev.w, a3);                                            \
            }                                                                         \
            float dot = (a0 + a1) + (a2 + a3);                                        \
            float s = fmaf(-2.0f, dot, e2g[c]);                                       \
            if (s < best || (s == best && c < bi)) { best = s; bi = c; }              \
        }                                                                             \
        _Pragma("unroll")                                                             \
        for (int m = 1; m <= 32; m <<= 1) {                                           \
            float ob = __shfl_xor(best, m);                                           \
            int oi = __shfl_xor(bi, m);                                               \
            if (ob < best || (ob == best && oi < bi)) { best = ob; bi = oi; }         \
        }                                                                             \
        out[(size_t)(ROW) * VQ_DIM + lane] = embed[(size_t)bi * VQ_DIM + lane];       \
    }

// ---------------- stage 1: two-product scan + gather + list1 append ----------------
__global__ __launch_bounds__(256, 4)
void vq_stage1(const float* __restrict__ x, const float* __restrict__ embed,
               unsigned char* ws, float* __restrict__ out) {
    __shared__ int idx_s[4][32];

    const int tid = threadIdx.x;
    const int lane = tid & 63;
    const int wave = tid >> 6;
    const int gwave = blockIdx.x * 4 + wave;
    const int R0 = gwave * 32;
    const int g = lane >> 4;
    const int res = lane & 15;
    const int khalf = g << 3;

    const short8* bsrc = (const short8*)(ws + WS_BH);
    const float* e2g = (const float*)(ws + WS_E2);
    unsigned* cnt = (unsigned*)(ws + WS_CNT);
    int* list = (int*)(ws + WS_LIST);

    short8 ah00, ah01, al00, al01, ah10, ah11, al10, al11;
    const int row0 = R0 + res;
    const int row1 = row0 + 16;
    MAKE_A(row0, 0, ah00, al00)
    MAKE_A(row0, 1, ah01, al01)
    MAKE_A(row1, 0, ah10, al10)
    MAKE_A(row1, 1, ah11, al11)

    unsigned m1k0[4], m2k0[4], m1k1[4], m2k1[4];
#pragma unroll
    for (int r = 0; r < 4; ++r) {
        m1k0[r] = 0xFFFFFFFFu; m2k0[r] = 0xFFFFFFFFu;
        m1k1[r] = 0xFFFFFFFFu; m2k1[r] = 0xFFFFFFFFu;
    }

#pragma unroll 2
    for (int ct = 0; ct < NT; ++ct) {
        const short8* bt = bsrc + (size_t)ct * TCH;
        short8 bh0 = bt[lane];
        short8 bh1 = bt[64 + lane];
        float e2c = e2g[ct * 16 + res] + 256.0f;
        unsigned ctu = (unsigned)ct;

        f32x4 acc0 = {e2c, e2c, e2c, e2c};
        acc0 = __builtin_amdgcn_mfma_f32_16x16x32_bf16(al00, bh0, acc0, 0, 0, 0);
        acc0 = __builtin_amdgcn_mfma_f32_16x16x32_bf16(al01, bh1, acc0, 0, 0, 0);
        acc0 = __builtin_amdgcn_mfma_f32_16x16x32_bf16(ah00, bh0, acc0, 0, 0, 0);
        acc0 = __builtin_amdgcn_mfma_f32_16x16x32_bf16(ah01, bh1, acc0, 0, 0, 0);

        f32x4 acc1 = {e2c, e2c, e2c, e2c};
        acc1 = __builtin_amdgcn_mfma_f32_16x16x32_bf16(al10, bh0, acc1, 0, 0, 0);
        acc1 = __builtin_amdgcn_mfma_f32_16x16x32_bf16(al11, bh1, acc1, 0, 0, 0);
        acc1 = __builtin_amdgcn_mfma_f32_16x16x32_bf16(ah10, bh0, acc1, 0, 0, 0);
        acc1 = __builtin_amdgcn_mfma_f32_16x16x32_bf16(ah11, bh1, acc1, 0, 0, 0);

        KEYUPD(acc0, m1k0, m2k0, ctu)
        KEYUPD(acc1, m1k1, m2k1, ctu)
    }

    unsigned res0[4], res1[4];
#pragma unroll
    for (int r = 0; r < 4; ++r) { res0[r] = (unsigned)res; res1[r] = res0[r]; }
#pragma unroll
    for (int m = 1; m <= 8; m <<= 1) {
        RED_STEP(m1k0, m2k0, res0, m)
        RED_STEP(m1k1, m2k1, res1, m)
    }

    unsigned fmask = 0;
    if (res == 0) {
#pragma unroll
        for (int r = 0; r < 4; ++r) {
            int rl0 = 4 * g + r;
            idx_s[wave][rl0] = (int)((m1k0[r] & 63u) * 16u + res0[r]);
            float s1 = __uint_as_float(m1k0[r] & 0xFFFFFFC0u);
            float s2 = __uint_as_float(m2k0[r] & 0xFFFFFFC0u);
            if (s2 - s1 < EPS1) fmask |= 1u << rl0;
            int rl1 = 16 + 4 * g + r;
            idx_s[wave][rl1] = (int)((m1k1[r] & 63u) * 16u + res1[r]);
            float t1f = __uint_as_float(m1k1[r] & 0xFFFFFFC0u);
            float t2f = __uint_as_float(m2k1[r] & 0xFFFFFFC0u);
            if (t2f - t1f < EPS1) fmask |= 1u << rl1;
        }
    }
    fmask |= (unsigned)__shfl_xor((int)fmask, 16);
    fmask |= (unsigned)__shfl_xor((int)fmask, 32);

    unsigned omask = 0;
    if (lane == 0 && fmask) {
        int n = __popc(fmask);
        unsigned pos = atomicAdd(cnt, (unsigned)n);
        unsigned m = fmask;
        int i = 0;
        while (m) {
            int b = __ffs(m) - 1;
            m &= m - 1;
            if (pos + (unsigned)i < LIST_CAP) list[pos + i] = R0 + b;
            else omask |= 1u << b;
            ++i;
        }
    }
    omask = (unsigned)__shfl((int)omask, 0);
    __syncthreads();

    // gather embed[idx] -> out (2 threads per row)
    const int orow = tid >> 1;
    const int ohalf = tid & 1;
    int code = idx_s[orow >> 5][orow & 31];
    const float4* ep = (const float4*)(embed + (size_t)code * VQ_DIM) + ohalf * 8;
    float4* op = (float4*)(out + (size_t)(blockIdx.x * 128 + orow) * VQ_DIM) + ohalf * 8;
#pragma unroll
    for (int j = 0; j < 8; ++j) op[j] = ep[j];

    // overflow safety net (expected never)
    while (omask) {
        int b = __ffs(omask) - 1;
        omask &= omask - 1;
        EXACT_ROW(R0 + b)
    }
}

// ---------------- stage 2: 3-product refine of list1, near-ties -> list2 ----------------
__global__ __launch_bounds__(256, 4)
void vq_stage2(const float* __restrict__ x, const float* __restrict__ embed,
               unsigned char* ws, float* __restrict__ out) {
    const int tid = threadIdx.x;
    const int lane = tid & 63;
    const int wave = tid >> 6;
    const int w = blockIdx.x * 4 + wave;

    const unsigned* cnt = (const unsigned*)(ws + WS_CNT);
    unsigned* cnt2 = (unsigned*)(ws + WS_CNT2);
    const int* list = (const int*)(ws + WS_LIST);
    int* list2 = (int*)(ws + WS_LIST2);
    const short8* bh = (const short8*)(ws + WS_BH);
    const short8* bl = (const short8*)(ws + WS_BL);
    const float* e2g = (const float*)(ws + WS_E2);

    int n = (int)*cnt;
    n = n < LIST_CAP ? n : LIST_CAP;
    int nw = (n + 31) >> 5;
    if (w >= nw) return;

    const int base = w * 32;
    const int g = lane >> 4;
    const int res = lane & 15;
    const int khalf = g << 3;

    const int i0 = base + res;
    const int i1 = base + 16 + res;
    const int row0 = list[i0 < n ? i0 : n - 1];
    const int row1 = list[i1 < n ? i1 : n - 1];

    short8 ah00, ah01, al00, al01, ah10, ah11, al10, al11;
    MAKE_A(row0, 0, ah00, al00)
    MAKE_A(row0, 1, ah01, al01)
    MAKE_A(row1, 0, ah10, al10)
    MAKE_A(row1, 1, ah11, al11)

    unsigned m1k0[4], m2k0[4], m1k1[4], m2k1[4];
#pragma unroll
    for (int r = 0; r < 4; ++r) {
        m1k0[r] = 0xFFFFFFFFu; m2k0[r] = 0xFFFFFFFFu;
        m1k1[r] = 0xFFFFFFFFu; m2k1[r] = 0xFFFFFFFFu;
    }

#pragma unroll 2
    for (int ct = 0; ct < NT; ++ct) {
        const short8* bht = bh + (size_t)ct * TCH;
        const short8* blt = bl + (size_t)ct * TCH;
        short8 bh0 = bht[lane];
        short8 bh1 = bht[64 + lane];
        short8 bl0 = blt[lane];
        short8 bl1 = blt[64 + lane];
        float e2c = e2g[ct * 16 + res] + 256.0f;
        unsigned ctu = (unsigned)ct;

        f32x4 acc0 = {e2c, e2c, e2c, e2c};
        acc0 = __builtin_amdgcn_mfma_f32_16x16x32_bf16(al00, bh0, acc0, 0, 0, 0);
        acc0 = __builtin_amdgcn_mfma_f32_16x16x32_bf16(al01, bh1, acc0, 0, 0, 0);
        acc0 = __builtin_amdgcn_mfma_f32_16x16x32_bf16(ah00, bl0, acc0, 0, 0, 0);
        acc0 = __builtin_amdgcn_mfma_f32_16x16x32_bf16(ah01, bl1, acc0, 0, 0, 0);
        acc0 = __builtin_amdgcn_mfma_f32_16x16x32_bf16(ah00, bh0, acc0, 0, 0, 0);
        acc0 = __builtin_amdgcn_mfma_f32_16x16x32_bf16(ah01, bh1, acc0, 0, 0, 0);

        f32x4 acc1 = {e2c, e2c, e2c, e2c};
        acc1 = __builtin_amdgcn_mfma_f32_16x16x32_bf16(al10, bh0, acc1, 0, 0, 0);
        acc1 = __builtin_amdgcn_mfma_f32_16x16x32_bf16(al11, bh1, acc1, 0, 0, 0);
        acc1 = __builtin_amdgcn_mfma_f32_16x16x32_bf16(ah10, bl0, acc1, 0, 0, 0);
        acc1 = __builtin_amdgcn_mfma_f32_16x16x32_bf16(ah11, bl1, acc1, 0, 0, 0);
        acc1 = __builtin_amdgcn_mfma_f32_16x16x32_bf16(ah10, bh0, acc1, 0, 0, 0);
        acc1 = __builtin_amdgcn_mfma_f32_16x16x32_bf16(ah11, bh1, acc1, 0, 0, 0);

        KEYUPD(acc0, m1k0, m2k0, ctu)
        KEYUPD(acc1, m1k1, m2k1, ctu)
    }

    unsigned res0[4], res1[4];
#pragma unroll
    for (int r = 0; r < 4; ++r) { res0[r] = (unsigned)res; res1[r] = res0[r]; }
#pragma unroll
    for (int m = 1; m <= 8; m <<= 1) {
        RED_STEP(m1k0, m2k0, res0, m)
        RED_STEP(m1k1, m2k1, res1, m)
    }

    int code0[4], code1[4];
    unsigned fmask = 0;
#pragma unroll
    for (int r = 0; r < 4; ++r) {
        code0[r] = (int)((m1k0[r] & 63u) * 16u + res0[r]);
        code1[r] = (int)((m1k1[r] & 63u) * 16u + res1[r]);
        float s1a = __uint_as_float(m1k0[r] & 0xFFFFFFC0u);
        float s2a = __uint_as_float(m2k0[r] & 0xFFFFFFC0u);
        if (s2a - s1a < EPS2) fmask |= 1u << (4 * g + r);
        float s1b = __uint_as_float(m1k1[r] & 0xFFFFFFC0u);
        float s2b = __uint_as_float(m2k1[r] & 0xFFFFFFC0u);
        if (s2b - s1b < EPS2) fmask |= 1u << (16 + 4 * g + r);
    }
    fmask |= (unsigned)__shfl_xor((int)fmask, 16);
    fmask |= (unsigned)__shfl_xor((int)fmask, 32);
    unsigned wmask = (unsigned)__shfl((int)fmask, 0);

    // write winners (2 lanes per gathered row)
    {
        const int q = lane >> 1;
        const int iq = base + q;
        const int rowq = list[iq < n ? iq : n - 1];
        const int setq = q >> 4;
        const int gq = (q & 15) >> 2;
        const int rq = q & 3;
        const int src = gq << 4;
        int a0 = __shfl(code0[0], src), a1 = __shfl(code0[1], src);
        int a2 = __shfl(code0[2], src), a3 = __shfl(code0[3], src);
        int b0 = __shfl(code1[0], src), b1 = __shfl(code1[1], src);
        int b2 = __shfl(code1[2], src), b3 = __shfl(code1[3], src);
        int cs0 = (rq == 0) ? a0 : (rq == 1) ? a1 : (rq == 2) ? a2 : a3;
        int cs1 = (rq == 0) ? b0 : (rq == 1) ? b1 : (rq == 2) ? b2 : b3;
        int my = setq ? cs1 : cs0;
        const float4* ep = (const float4*)(embed + (size_t)my * VQ_DIM) + (lane & 1) * 8;
        float4* op = (float4*)(out + (size_t)rowq * VQ_DIM) + (lane & 1) * 8;
#pragma unroll
        for (int j = 0; j < 8; ++j) op[j] = ep[j];
    }

    // append near-ties to list2 (one atomic per wave); overflow -> serial exact
    unsigned omask = 0;
    if (lane == 0 && wmask) {
        int nt2 = __popc(wmask);
        unsigned pos = atomicAdd(cnt2, (unsigned)nt2);
        unsigned m = wmask;
        int i = 0;
        while (m) {
            int b = __ffs(m) - 1;
            m &= m - 1;
            int ib = base + b;
            int rowb = list[ib < n ? ib : n - 1];
            if (pos + (unsigned)i < LIST2_CAP) list2[pos + i] = rowb;
            else omask |= 1u << b;
            ++i;
        }
    }
    omask = (unsigned)__shfl((int)omask, 0);
    while (omask) {
        int b = __ffs(omask) - 1;
        omask &= omask - 1;
        int ib = base + b;
        int rowb = list[ib < n ? ib : n - 1];
        EXACT_ROW(rowb)
    }
}

// ---------------- stage 3: exact fp32, one row per wave ----------------
__global__ __launch_bounds__(256, 4)
void vq_stage3(const float* __restrict__ x, const float* __restrict__ embed,
               unsigned char* ws, float* __restrict__ out) {
    const int lane = threadIdx.x & 63;
    const int wave = threadIdx.x >> 6;
    const int w = blockIdx.x * 4 + wave;

    const unsigned* cnt2 = (const unsigned*)(ws + WS_CNT2);
    const int* list2 = (const int*)(ws + WS_LIST2);
    const float* e2g = (const float*)(ws + WS_E2);

    int n = (int)*cnt2;
    n = n < LIST2_CAP ? n : LIST2_CAP;
    for (int i = w; i < n; i += NWAVES_S3) {
        int row = list2[i];
        EXACT_ROW(row)
    }
}

// ---------------- fallback (round-1 fp32, only if ws too small) ----------------
__global__ __launch_bounds__(256, 4)
void vq_fallback(const float* __restrict__ x, const float* __restrict__ embed,
                 float* __restrict__ out) {
    __shared__ float e2s[VQ_K];
    const int tid = threadIdx.x;
    for (int c = tid; c < VQ_K; c += 256) {
        const float4* ep = (const float4*)(embed + c * VQ_DIM);
        float s = 0.0f;
#pragma unroll
        for (int j = 0; j < VQ_DIM / 4; ++j) {
            float4 v = ep[j];
            s = fmaf(v.x, v.x, s); s = fmaf(v.y, v.y, s);
            s = fmaf(v.z, v.z, s); s = fmaf(v.w, v.w, s);
        }
        e2s[c] = s;
    }
    __syncthreads();
    const int row = blockIdx.x * 256 + tid;
    float xr[VQ_DIM];
    const float4* xp = (const float4*)(x + (size_t)row * VQ_DIM);
#pragma unroll
    for (int j = 0; j < VQ_DIM / 4; ++j) {
        float4 v = xp[j];
        xr[4 * j] = v.x; xr[4 * j + 1] = v.y; xr[4 * j + 2] = v.z; xr[4 * j + 3] = v.w;
    }
    float best = __builtin_inff();
    int bidx = 0;
    for (int c = 0; c < VQ_K; ++c) {
        const float4* ep = (const float4*)(embed + c * VQ_DIM);
        float a0 = 0, a1 = 0, a2 = 0, a3 = 0;
#pragma unroll
        for (int j = 0; j < VQ_DIM / 4; ++j) {
            float4 v = ep[j];
            a0 = fmaf(xr[4 * j], v.x, a0);
            a1 = fmaf(xr[4 * j + 1], v.y, a1);
            a2 = fmaf(xr[4 * j + 2], v.z, a2);
            a3 = fmaf(xr[4 * j + 3], v.w, a3);
        }
        float score = fmaf(-2.0f, (a0 + a1) + (a2 + a3), e2s[c]);
        if (score < best) { best = score; bidx = c; }
    }
    const float4* bp = (const float4*)(embed + (size_t)bidx * VQ_DIM);
    float4* op = (float4*)(out + (size_t)row * VQ_DIM);
#pragma unroll
    for (int j = 0; j < VQ_DIM / 4; ++j) op[j] = bp[j];
}

extern "C" void kernel_launch(void* const* d_in, const int* in_sizes, int n_in,
                              void* d_out, int out_size, void* d_ws, size_t ws_size,
                              hipStream_t stream) {
    const float* x = (const float*)d_in[0];
    const float* embed = (const float*)d_in[1];
    float* out = (float*)d_out;
    if (ws_size < WS_NEEDED) {
        hipLaunchKernelGGL(vq_fallback, dim3(VQ_N / 256), dim3(256), 0, stream, x, embed, out);
        return;
    }
    unsigned char* ws = (unsigned char*)d_ws;
    hipLaunchKernelGGL(vq_prep, dim3(70), dim3(256), 0, stream, embed, ws);
    hipLaunchKernelGGL(vq_stage1, dim3(VQ_N / 128), dim3(256), 0, stream, x, embed, ws, out);
    hipLaunchKernelGGL(vq_stage2, dim3(VQ_N / 128), dim3(256), 0, stream, x, embed, ws, out);
    hipLaunchKernelGGL(vq_stage3, dim3(NWAVES_S3 / 4), dim3(256), 0, stream, x, embed, ws, out);
}

// Round 15
// 170.189 us; speedup vs baseline: 6.4537x; 1.2343x over previous
//
#include <hip/hip_runtime.h>

// VQ: N=262144 rows, DIM=64, K=1024 codes.
// Single fused compute kernel (champion R9 structure, zero-LDS):
//   16x16x32 bf16 MFMA, 3-product hi/lo split (xl.eh + xh.el + xh.eh),
//   acc init = ||e||^2 + 256 (positive scores -> raw bits order-preserving),
//   key = (bits & ~63) | ct; top2 via v_med3_u32 (3 ops/score).
//   32 rows/wave, two 16-row A-sets share each B read; B tiles from L2,
//   sequential order, compiler unroll-2. Winner publish + gather fully
//   in-wave via shfl (no LDS, no barriers). Rows with top2 margin <
//   FLAG_EPS (~0.15%) exactly re-solved in-wave (fp32, no reg array).
// np.argmin first-min tie-break preserved (ct in key LSBs + residue
//   tie-break; near-ties re-solved exactly with index-ordered selection).

#define VQ_N 262144
#define VQ_DIM 64
#define VQ_K 1024
#define NT 64                   // 64 code-tiles of 16 codes
#define TCH 128                 // 16B chunks per hi (or lo) tile = 2048 B
#define FLAG_EPS 1.2e-2f

typedef short short8 __attribute__((ext_vector_type(8)));
typedef float f32x4 __attribute__((ext_vector_type(4)));

// ws layout (bytes)
#define WS_BH    0                   // 131072 (e hi fragments)
#define WS_BL    (128*1024)          // 131072 (e lo fragments)
#define WS_E2    (256*1024)          // float[1024] raw ||e||^2 (resolve)
#define WS_E2P   (260*1024)          // float[1024] ||e||^2 + 256 (scan init)
#define WS_NEEDED (264*1024)

static __device__ __forceinline__ unsigned short f2bf_rtne(float f) {
    unsigned u = __float_as_uint(f);
    unsigned r = u + 0x7FFFu + ((u >> 16) & 1u);
    return (unsigned short)(r >> 16);
}
static __device__ __forceinline__ float bf2f(unsigned short h) {
    return __uint_as_float(((unsigned)h) << 16);
}
static __device__ __forceinline__ unsigned med3u(unsigned a, unsigned b, unsigned c) {
    unsigned d;
    asm("v_med3_u32 %0, %1, %2, %3" : "=v"(d) : "v"(a), "v"(b), "v"(c));
    return d;
}

// ---------------- prep: B fragments (hi/lo), e2, e2+256 ----------------
// chunk c = ct*128 + kc*64 + l : 8 bf16 of embed[ct*16+(l&15)][kc*32+(l>>4)*8+j]
__global__ void vq_prep(const float* __restrict__ embed, unsigned char* ws) {
    int t = blockIdx.x * 256 + threadIdx.x;     // 0 .. 17919
    if (t < 16384) {
        int arr = t >> 13;                      // 0 = hi, 1 = lo
        int c = t & 8191;
        int ct = c >> 7;
        int kc = (c >> 6) & 1;
        int l = c & 63;
        int code = ct * 16 + (l & 15);
        int kbase = kc * 32 + ((l >> 4) << 3);
        const float* ep = embed + (size_t)code * VQ_DIM + kbase;
        short8 pack;
#pragma unroll
        for (int j = 0; j < 8; ++j) {
            float v = ep[j];
            unsigned short h = f2bf_rtne(v);
            pack[j] = arr ? (short)f2bf_rtne(v - bf2f(h)) : (short)h;
        }
        ((short8*)(ws + (arr ? WS_BL : WS_BH)))[c] = pack;
    } else if (t < 16384 + VQ_K) {
        int code = t - 16384;
        const float* ep = embed + (size_t)code * VQ_DIM;
        float a0 = 0, a1 = 0, a2 = 0, a3 = 0;
#pragma unroll
        for (int j = 0; j < VQ_DIM; j += 4) {
            a0 = fmaf(ep[j], ep[j], a0);
            a1 = fmaf(ep[j + 1], ep[j + 1], a1);
            a2 = fmaf(ep[j + 2], ep[j + 2], a2);
            a3 = fmaf(ep[j + 3], ep[j + 3], a3);
        }
        float e2 = (a0 + a1) + (a2 + a3);
        ((float*)(ws + WS_E2))[code] = e2;
        ((float*)(ws + WS_E2P))[code] = e2 + 256.0f;
    }
}

// ---------------- stage 1: scan + in-wave gather + in-wave exact resolve ----------------
__global__ __launch_bounds__(256, 4)
void vq_stage1(const float* __restrict__ x, const float* __restrict__ embed,
               unsigned char* ws, float* __restrict__ out) {
    const int tid = threadIdx.x;
    const int lane = tid & 63;
    const int wave = tid >> 6;
    const int gwave = blockIdx.x * 4 + wave;   // owns 32 rows
    const int R0 = gwave * 32;
    const int g = lane >> 4;            // 0..3
    const int res = lane & 15;
    const int khalf = g << 3;           // A-frag k-offset within 32-chunk

    const short8* bh = (const short8*)(ws + WS_BH);
    const short8* bl = (const short8*)(ws + WS_BL);
    const float* e2g = (const float*)(ws + WS_E2);
    const float* e2p = (const float*)(ws + WS_E2P);

    // ---- A fragments: -2x hi/lo, two 16-row sets, named scalars ----
    short8 ah00, ah01, al00, al01, ah10, ah11, al10, al11;
#define MAKE_A(ROW, KC, AH, AL)                                             \
    {                                                                       \
        const float4* p4 = (const float4*)(x + (size_t)(ROW) * VQ_DIM +     \
                                           (KC) * 32 + khalf);              \
        float4 v0 = p4[0], v1 = p4[1];                                      \
        float q0 = -2.0f * v0.x, q1 = -2.0f * v0.y, q2 = -2.0f * v0.z,      \
              q3 = -2.0f * v0.w, q4 = -2.0f * v1.x, q5 = -2.0f * v1.y,      \
              q6 = -2.0f * v1.z, q7 = -2.0f * v1.w;                         \
        unsigned short h0 = f2bf_rtne(q0), h1 = f2bf_rtne(q1),              \
                       h2 = f2bf_rtne(q2), h3 = f2bf_rtne(q3),              \
                       h4 = f2bf_rtne(q4), h5 = f2bf_rtne(q5),              \
                       h6 = f2bf_rtne(q6), h7 = f2bf_rtne(q7);              \
        AH[0] = (short)h0; AH[1] = (short)h1; AH[2] = (short)h2;            \
        AH[3] = (short)h3; AH[4] = (short)h4; AH[5] = (short)h5;            \
        AH[6] = (short)h6; AH[7] = (short)h7;                               \
        AL[0] = (short)f2bf_rtne(q0 - bf2f(h0));                            \
        AL[1] = (short)f2bf_rtne(q1 - bf2f(h1));                            \
        AL[2] = (short)f2bf_rtne(q2 - bf2f(h2));                            \
        AL[3] = (short)f2bf_rtne(q3 - bf2f(h3));                            \
        AL[4] = (short)f2bf_rtne(q4 - bf2f(h4));                            \
        AL[5] = (short)f2bf_rtne(q5 - bf2f(h5));                            \
        AL[6] = (short)f2bf_rtne(q6 - bf2f(h6));                            \
        AL[7] = (short)f2bf_rtne(q7 - bf2f(h7));                            \
    }
    const int row0 = R0 + res;
    const int row1 = row0 + 16;
    MAKE_A(row0, 0, ah00, al00)
    MAKE_A(row0, 1, ah01, al01)
    MAKE_A(row1, 0, ah10, al10)
    MAKE_A(row1, 1, ah11, al11)
#undef MAKE_A

    unsigned m1k0[4], m2k0[4], m1k1[4], m2k1[4];
#pragma unroll
    for (int r = 0; r < 4; ++r) {
        m1k0[r] = 0xFFFFFFFFu; m2k0[r] = 0xFFFFFFFFu;
        m1k1[r] = 0xFFFFFFFFu; m2k1[r] = 0xFFFFFFFFu;
    }

    // ---- main scan: 3-product, sequential tiles, compiler unroll-2 ----
#pragma unroll 2
    for (int ct = 0; ct < NT; ++ct) {
        const short8* bht = bh + (size_t)ct * TCH;
        const short8* blt = bl + (size_t)ct * TCH;
        short8 bh0 = bht[lane];
        short8 bh1 = bht[64 + lane];
        short8 bl0 = blt[lane];
        short8 bl1 = blt[64 + lane];
        float e2c = e2p[ct * 16 + res];
        unsigned ctu = (unsigned)ct;

        f32x4 acc0 = {e2c, e2c, e2c, e2c};
        acc0 = __builtin_amdgcn_mfma_f32_16x16x32_bf16(al00, bh0, acc0, 0, 0, 0);
        acc0 = __builtin_amdgcn_mfma_f32_16x16x32_bf16(al01, bh1, acc0, 0, 0, 0);
        acc0 = __builtin_amdgcn_mfma_f32_16x16x32_bf16(ah00, bl0, acc0, 0, 0, 0);
        acc0 = __builtin_amdgcn_mfma_f32_16x16x32_bf16(ah01, bl1, acc0, 0, 0, 0);
        acc0 = __builtin_amdgcn_mfma_f32_16x16x32_bf16(ah00, bh0, acc0, 0, 0, 0);
        acc0 = __builtin_amdgcn_mfma_f32_16x16x32_bf16(ah01, bh1, acc0, 0, 0, 0);

        f32x4 acc1 = {e2c, e2c, e2c, e2c};
        acc1 = __builtin_amdgcn_mfma_f32_16x16x32_bf16(al10, bh0, acc1, 0, 0, 0);
        acc1 = __builtin_amdgcn_mfma_f32_16x16x32_bf16(al11, bh1, acc1, 0, 0, 0);
        acc1 = __builtin_amdgcn_mfma_f32_16x16x32_bf16(ah10, bl0, acc1, 0, 0, 0);
        acc1 = __builtin_amdgcn_mfma_f32_16x16x32_bf16(ah11, bl1, acc1, 0, 0, 0);
        acc1 = __builtin_amdgcn_mfma_f32_16x16x32_bf16(ah10, bh0, acc1, 0, 0, 0);
        acc1 = __builtin_amdgcn_mfma_f32_16x16x32_bf16(ah11, bh1, acc1, 0, 0, 0);

        // top2 update: key gen (v_and_or) + med3 + min = 3 ops/score
#pragma unroll
        for (int r = 0; r < 4; ++r) {
            unsigned key = (__float_as_uint(acc0[r]) & 0xFFFFFFC0u) | ctu;
            m2k0[r] = med3u(m1k0[r], m2k0[r], key);
            m1k0[r] = m1k0[r] < key ? m1k0[r] : key;
        }
#pragma unroll
        for (int r = 0; r < 4; ++r) {
            unsigned key = (__float_as_uint(acc1[r]) & 0xFFFFFFC0u) | ctu;
            m2k1[r] = med3u(m1k1[r], m2k1[r], key);
            m1k1[r] = m1k1[r] < key ? m1k1[r] : key;
        }
    }

    // ---- reduce over the 16 codes (lanes within each 16-group) ----
    unsigned res0[4], res1[4];
#pragma unroll
    for (int r = 0; r < 4; ++r) { res0[r] = (unsigned)res; res1[r] = res0[r]; }
#define RED_STEP(M1, M2, RES, m)                                                      \
    {                                                                                 \
        _Pragma("unroll")                                                             \
        for (int r = 0; r < 4; ++r) {                                                 \
            unsigned ok = (unsigned)__shfl_xor((int)M1[r], m);                        \
            unsigned ok2 = (unsigned)__shfl_xor((int)M2[r], m);                       \
            unsigned orr = (unsigned)__shfl_xor((int)RES[r], m);                      \
            unsigned t1 = M1[r] > ok ? M1[r] : ok;                                    \
            unsigned c2 = ok2 < t1 ? ok2 : t1;                                        \
            M2[r] = M2[r] < c2 ? M2[r] : c2;                                          \
            bool take = (ok < M1[r]) || (ok == M1[r] && orr < RES[r]);                \
            if (take) { M1[r] = ok; RES[r] = orr; }                                   \
        }                                                                             \
    }
#pragma unroll
    for (int m = 1; m <= 8; m <<= 1) {
        RED_STEP(m1k0, m2k0, res0, m)
        RED_STEP(m1k1, m2k1, res1, m)
    }
#undef RED_STEP

    // ---- winner codes + margin flags (all lanes of a group agree) ----
    int code0[4], code1[4];
    unsigned fmask = 0;
#pragma unroll
    for (int r = 0; r < 4; ++r) {
        code0[r] = (int)((m1k0[r] & 63u) * 16u + res0[r]);
        code1[r] = (int)((m1k1[r] & 63u) * 16u + res1[r]);
        float s1a = __uint_as_float(m1k0[r] & 0xFFFFFFC0u);
        float s2a = __uint_as_float(m2k0[r] & 0xFFFFFFC0u);
        if (s2a - s1a < FLAG_EPS) fmask |= 1u << (4 * g + r);
        float s1b = __uint_as_float(m1k1[r] & 0xFFFFFFC0u);
        float s2b = __uint_as_float(m2k1[r] & 0xFFFFFFC0u);
        if (s2b - s1b < FLAG_EPS) fmask |= 1u << (16 + 4 * g + r);
    }
    fmask |= (unsigned)__shfl_xor((int)fmask, 16);
    fmask |= (unsigned)__shfl_xor((int)fmask, 32);
    unsigned wmask = fmask;             // full 32-row flag mask on every lane

    // ---- in-wave gather: lane handles row q = lane>>1, half = lane&1 ----
    {
        const int q = lane >> 1;            // 0..31
        const int setq = q >> 4;
        const int gq = (q & 15) >> 2;
        const int rq = q & 3;
        const int src = gq << 4;
        int a0 = __shfl(code0[0], src), a1 = __shfl(code0[1], src);
        int a2 = __shfl(code0[2], src), a3 = __shfl(code0[3], src);
        int b0 = __shfl(code1[0], src), b1 = __shfl(code1[1], src);
        int b2 = __shfl(code1[2], src), b3 = __shfl(code1[3], src);
        int cs0 = (rq == 0) ? a0 : (rq == 1) ? a1 : (rq == 2) ? a2 : a3;
        int cs1 = (rq == 0) ? b0 : (rq == 1) ? b1 : (rq == 2) ? b2 : b3;
        int my = setq ? cs1 : cs0;
        const float4* ep = (const float4*)(embed + (size_t)my * VQ_DIM) + (lane & 1) * 8;
        float4* op = (float4*)(out + (size_t)(R0 + q) * VQ_DIM) + (lane & 1) * 8;
#pragma unroll
        for (int j = 0; j < 8; ++j) op[j] = ep[j];
    }

    // ---- in-wave exact fp32 re-solve of flagged rows (~0.15%) ----
    while (wmask) {
        int b = __ffs(wmask) - 1;
        wmask &= wmask - 1;
        int row = R0 + b;
        const float4* xr4 = (const float4*)(x + (size_t)row * VQ_DIM);
        float best = __builtin_inff();
        int bi = VQ_K;
        for (int t = 0; t < VQ_K / 64; ++t) {
            int c = t * 64 + lane;
            const float4* ep4 = (const float4*)(embed + (size_t)c * VQ_DIM);
            float a0 = 0, a1 = 0, a2 = 0, a3 = 0;
#pragma unroll
            for (int j = 0; j < VQ_DIM / 4; ++j) {
                float4 xv = xr4[j];
                float4 ev = ep4[j];
                a0 = fmaf(xv.x, ev.x, a0);
                a1 = fmaf(xv.y, ev.y, a1);
                a2 = fmaf(xv.z, ev.z, a2);
                a3 = fmaf(xv.w, ev.w, a3);
            }
            float dot = (a0 + a1) + (a2 + a3);
            float s = fmaf(-2.0f, dot, e2g[c]);
            if (s < best || (s == best && c < bi)) { best = s; bi = c; }
        }
#pragma unroll
        for (int m = 1; m <= 32; m <<= 1) {
            float ob = __shfl_xor(best, m);
            int oi = __shfl_xor(bi, m);
            if (ob < best || (ob == best && oi < bi)) { best = ob; bi = oi; }
        }
        out[(size_t)row * VQ_DIM + lane] = embed[(size_t)bi * VQ_DIM + lane];
    }
}

// ---------------- fallback (round-1 fp32, only if ws too small) ----------------
__global__ __launch_bounds__(256, 4)
void vq_fallback(const float* __restrict__ x, const float* __restrict__ embed,
                 float* __restrict__ out) {
    __shared__ float e2s[VQ_K];
    const int tid = threadIdx.x;
    for (int c = tid; c < VQ_K; c += 256) {
        const float4* ep = (const float4*)(embed + c * VQ_DIM);
        float s = 0.0f;
#pragma unroll
        for (int j = 0; j < VQ_DIM / 4; ++j) {
            float4 v = ep[j];
            s = fmaf(v.x, v.x, s); s = fmaf(v.y, v.y, s);
            s = fmaf(v.z, v.z, s); s = fmaf(v.w, v.w, s);
        }
        e2s[c] = s;
    }
    __syncthreads();
    const int row = blockIdx.x * 256 + tid;
    float xr[VQ_DIM];
    const float4* xp = (const float4*)(x + (size_t)row * VQ_DIM);
#pragma unroll
    for (int j = 0; j < VQ_DIM / 4; ++j) {
        float4 v = xp[j];
        xr[4 * j] = v.x; xr[4 * j + 1] = v.y; xr[4 * j + 2] = v.z; xr[4 * j + 3] = v.w;
    }
    float best = __builtin_inff();
    int bidx = 0;
    for (int c = 0; c < VQ_K; ++c) {
        const float4* ep = (const float4*)(embed + c * VQ_DIM);
        float a0 = 0, a1 = 0, a2 = 0, a3 = 0;
#pragma unroll
        for (int j = 0; j < VQ_DIM / 4; ++j) {
            float4 v = ep[j];
            a0 = fmaf(xr[4 * j], v.x, a0);
            a1 = fmaf(xr[4 * j + 1], v.y, a1);
            a2 = fmaf(xr[4 * j + 2], v.z, a2);
            a3 = fmaf(xr[4 * j + 3], v.w, a3);
        }
        float score = fmaf(-2.0f, (a0 + a1) + (a2 + a3), e2s[c]);
        if (score < best) { best = score; bidx = c; }
    }
    const float4* bp = (const float4*)(embed + (size_t)bidx * VQ_DIM);
    float4* op = (float4*)(out + (size_t)row * VQ_DIM);
#pragma unroll
    for (int j = 0; j < VQ_DIM / 4; ++j) op[j] = bp[j];
}

extern "C" void kernel_launch(void* const* d_in, const int* in_sizes, int n_in,
                              void* d_out, int out_size, void* d_ws, size_t ws_size,
                              hipStream_t stream) {
    const float* x = (const float*)d_in[0];
    const float* embed = (const float*)d_in[1];
    float* out = (float*)d_out;
    if (ws_size < WS_NEEDED) {
        hipLaunchKernelGGL(vq_fallback, dim3(VQ_N / 256), dim3(256), 0, stream, x, embed, out);
        return;
    }
    unsigned char* ws = (unsigned char*)d_ws;
    hipLaunchKernelGGL(vq_prep, dim3(70), dim3(256), 0, stream, embed, ws);
    hipLaunchKernelGGL(vq_stage1, dim3(VQ_N / 128), dim3(256), 0, stream, x, embed, ws, out);
}